// Round 3
// baseline (675.198 us; speedup 1.0000x reference)
//
#include <hip/hip_runtime.h>

#define NB 20000
#define EB 320000
#define DIN 128
#define H1D 256
#define H2D 256
#define DOUTD 128

#define TILE_SHIFT 12           // src tile = 4096 rows (4 MB at F=256 -> fits per-XCD L2)
#define NT 5                    // ceil(20000 / 4096)
#define NBINS (NB * NT)         // 100000 (key = dst*NT + src_tile)
#define RPW 8                   // rows per wave; 40000 = 1250 blocks * 4 waves * 8

// ---------------------------------------------------------------------------
// Setup: key histogram -> scan (tile-CSR) -> dinv -> counting-sort scatter of
// edge records int2{src, w_bits}. Rebuilt every call (deterministic).
// ---------------------------------------------------------------------------

__global__ void zero_kernel(int* __restrict__ p, int n) {
    int t = blockIdx.x * blockDim.x + threadIdx.x;
    if (t < n) p[t] = 0;
}

__global__ void hist_kernel(const int* __restrict__ src, const int* __restrict__ dst,
                            int* __restrict__ bins) {
    int t = blockIdx.x * blockDim.x + threadIdx.x;
    if (t < EB) {
        int key = dst[t] * NT + (src[t] >> TILE_SHIFT);
        atomicAdd(&bins[key], 1);
    }
}

// Single-block exclusive scan over NBINS counts -> rs[NBINS+1], cursor copy.
__global__ __launch_bounds__(1024) void scan_kernel(const int* __restrict__ bins,
                                                    int* __restrict__ rs,
                                                    int* __restrict__ cursor) {
    __shared__ int sums[1024];
    const int CH = (NBINS + 1023) / 1024;  // 98
    int t = threadIdx.x;
    int base = t * CH;
    int s = 0;
    for (int j = 0; j < CH; ++j) {
        int i = base + j;
        if (i < NBINS) s += bins[i];
    }
    sums[t] = s;
    __syncthreads();
    for (int off = 1; off < 1024; off <<= 1) {
        int v = (t >= off) ? sums[t - off] : 0;
        __syncthreads();
        sums[t] += v;
        __syncthreads();
    }
    int run = sums[t] - s;  // exclusive prefix of this chunk
    for (int j = 0; j < CH; ++j) {
        int i = base + j;
        if (i < NBINS) {
            rs[i] = run;
            cursor[i] = run;
            run += bins[i];
        }
    }
    if (t == 1023) rs[NBINS] = sums[1023];
}

__global__ void dinv_kernel(const int* __restrict__ rs, float* __restrict__ dinv) {
    int i = blockIdx.x * blockDim.x + threadIdx.x;
    if (i < NB) {
        int deg = rs[(i + 1) * NT] - rs[i * NT];  // in-degree
        dinv[i] = rsqrtf((float)deg + 1.0f);      // +1 self loop
    }
}

__global__ void scatter_kernel(const int* __restrict__ src, const int* __restrict__ dst,
                               const float* __restrict__ dinv,
                               int* __restrict__ cursor, int2* __restrict__ edges) {
    int t = blockIdx.x * blockDim.x + threadIdx.x;
    if (t < EB) {
        int d = dst[t], s = src[t];
        int key = d * NT + (s >> TILE_SHIFT);
        int p = atomicAdd(&cursor[key], 1);
        edges[p] = make_int2(s, __float_as_int(dinv[s] * dinv[d]));
    }
}

// ---------------------------------------------------------------------------
// Tile-major aggregation. One wave owns RPW=8 rows (acc in registers); outer
// loop over src tiles so all resident waves gather from the same <=4 MB
// window -> per-XCD L2 hits instead of L3/fabric traffic. Rows processed in
// pairs for MLP>=2.
// ---------------------------------------------------------------------------

__device__ inline void vload(float (&d)[4], const float* p) {
    float4 t = *(const float4*)p; d[0] = t.x; d[1] = t.y; d[2] = t.z; d[3] = t.w;
}
__device__ inline void vload(float (&d)[2], const float* p) {
    float2 t = *(const float2*)p; d[0] = t.x; d[1] = t.y;
}
__device__ inline void vstore(float* p, const float (&d)[4]) {
    *(float4*)p = make_float4(d[0], d[1], d[2], d[3]);
}
__device__ inline void vstore(float* p, const float (&d)[2]) {
    *(float2*)p = make_float2(d[0], d[1]);
}

template <int F, int VEC>
__device__ inline void drain(const float* __restrict__ hsrc, const int2* __restrict__ edges,
                             int e0, int e1, float (&acc)[VEC]) {
    int e = e0;
    for (; e + 2 <= e1; e += 2) {
        int2 r0 = edges[e], r1 = edges[e + 1];
        float t0[VEC], t1[VEC];
        vload(t0, hsrc + (size_t)r0.x * F);
        vload(t1, hsrc + (size_t)r1.x * F);
        float w0 = __int_as_float(r0.y), w1 = __int_as_float(r1.y);
#pragma unroll
        for (int v = 0; v < VEC; ++v) acc[v] = fmaf(t0[v], w0, acc[v]);
#pragma unroll
        for (int v = 0; v < VEC; ++v) acc[v] = fmaf(t1[v], w1, acc[v]);
    }
    if (e < e1) {
        int2 r0 = edges[e];
        float t0[VEC];
        vload(t0, hsrc + (size_t)r0.x * F);
        float w0 = __int_as_float(r0.y);
#pragma unroll
        for (int v = 0; v < VEC; ++v) acc[v] = fmaf(t0[v], w0, acc[v]);
    }
}

template <int F, bool BIAS, bool PRELU>
__global__ __launch_bounds__(256) void agg2_kernel(
    const float* __restrict__ h, float* __restrict__ out,
    const int* __restrict__ rs, const int2* __restrict__ edges,
    const float* __restrict__ dinv, const float* __restrict__ bias,
    const float* __restrict__ pa, int nrows) {
    constexpr int VEC = F / 64;
    int w = blockIdx.x * 4 + (threadIdx.x >> 6);
    int lane = threadIdx.x & 63;
    int base = w * RPW;
    if (base >= nrows) return;  // grids chosen so full waves only (exact divide)
    int hb = (base >= NB) ? NB : 0;    // batch-1 rows: CSR index is row-NB
    int ic = base - hb;
    const float* hsrc = h + (size_t)hb * F + lane * VEC;

    float acc[RPW][VEC];
#pragma unroll
    for (int r = 0; r < RPW; ++r) {
        float dv = dinv[ic + r];
        float t[VEC];
        vload(t, h + (size_t)(base + r) * F + lane * VEC);
#pragma unroll
        for (int v = 0; v < VEC; ++v) acc[r][v] = t[v] * (dv * dv);
    }

    for (int tt = 0; tt < NT; ++tt) {
#pragma unroll
        for (int r = 0; r < RPW; r += 2) {
            int ka = (ic + r) * NT + tt;
            int kb = ka + NT;
            int a0 = rs[ka], a1 = rs[ka + 1];
            int b0 = rs[kb], b1 = rs[kb + 1];
            while (a0 < a1 && b0 < b1) {  // wave-uniform bounds
                int2 ra = edges[a0++], rb = edges[b0++];
                float ta[VEC], tb[VEC];
                vload(ta, hsrc + (size_t)ra.x * F);
                vload(tb, hsrc + (size_t)rb.x * F);
                float wa = __int_as_float(ra.y), wb = __int_as_float(rb.y);
#pragma unroll
                for (int v = 0; v < VEC; ++v) acc[r][v] = fmaf(ta[v], wa, acc[r][v]);
#pragma unroll
                for (int v = 0; v < VEC; ++v) acc[r + 1][v] = fmaf(tb[v], wb, acc[r + 1][v]);
            }
            drain<F, VEC>(hsrc, edges, a0, a1, acc[r]);
            drain<F, VEC>(hsrc, edges, b0, b1, acc[r + 1]);
        }
    }

    float bv[VEC];
    if (BIAS) vload(bv, bias + lane * VEC);
    float a = PRELU ? *pa : 0.0f;
#pragma unroll
    for (int r = 0; r < RPW; ++r) {
#pragma unroll
        for (int v = 0; v < VEC; ++v) {
            float x = acc[r][v];
            if (BIAS) x += bv[v];
            if (PRELU) x = (x >= 0.0f) ? x : a * x;
            acc[r][v] = x;
        }
        vstore(out + (size_t)(base + r) * F + lane * VEC, acc[r]);
    }
}

// ---------------------------------------------------------------------------
// FP32 GEMM: C[M,Nc] = A[M,K] @ W[K,Nc] (+bias) (+prelu).
// 64x64 tile, BK=16, 256 threads, 4x4 microtile. VALU-bound (no fp32 MFMA).
// ---------------------------------------------------------------------------
template <bool BIAS, bool PRELU>
__global__ __launch_bounds__(256) void gemm_kernel(const float* __restrict__ A, int M, int K,
                                                   const float* __restrict__ W, int Nc,
                                                   const float* __restrict__ bias,
                                                   const float* __restrict__ pa,
                                                   float* __restrict__ C) {
    __shared__ alignas(16) float As[16][68];
    __shared__ alignas(16) float Bs[16][68];
    int t = threadIdx.x;
    int bm = blockIdx.x * 64;
    int bn = blockIdx.y * 64;
    int tx = t & 15, ty = t >> 4;
    int m0 = ty * 4, n0 = tx * 4;
    int ar = t >> 2, ac4 = (t & 3) * 4;
    int br = t >> 4, bc4 = (t & 15) * 4;

    float acc[4][4] = {};

    for (int k0 = 0; k0 < K; k0 += 16) {
        float4 av = make_float4(0.f, 0.f, 0.f, 0.f);
        int arow = bm + ar;
        if (arow < M) av = *(const float4*)&A[(size_t)arow * K + k0 + ac4];
        As[ac4 + 0][ar] = av.x;
        As[ac4 + 1][ar] = av.y;
        As[ac4 + 2][ar] = av.z;
        As[ac4 + 3][ar] = av.w;
        float4 bv = *(const float4*)&W[(size_t)(k0 + br) * Nc + bn + bc4];
        *(float4*)&Bs[br][bc4] = bv;
        __syncthreads();
#pragma unroll
        for (int k = 0; k < 16; ++k) {
            float4 av4 = *(const float4*)&As[k][m0];
            float4 bv4 = *(const float4*)&Bs[k][n0];
            float a_[4] = {av4.x, av4.y, av4.z, av4.w};
            float b_[4] = {bv4.x, bv4.y, bv4.z, bv4.w};
#pragma unroll
            for (int i = 0; i < 4; ++i)
#pragma unroll
                for (int j = 0; j < 4; ++j)
                    acc[i][j] = fmaf(a_[i], b_[j], acc[i][j]);
        }
        __syncthreads();
    }

    float pav = 0.0f;
    if (PRELU) pav = *pa;
#pragma unroll
    for (int i = 0; i < 4; ++i) {
        int row = bm + m0 + i;
        if (row < M) {
            float v[4];
#pragma unroll
            for (int j = 0; j < 4; ++j) {
                float x = acc[i][j];
                if (BIAS) x += bias[bn + n0 + j];
                if (PRELU) x = (x >= 0.0f) ? x : pav * x;
                v[j] = x;
            }
            *(float4*)&C[(size_t)row * Nc + bn + n0] = make_float4(v[0], v[1], v[2], v[3]);
        }
    }
}

// ---------------------------------------------------------------------------

static inline char* carve(char*& p, size_t bytes) {
    char* r = p;
    p += (bytes + 255) & ~(size_t)255;
    return r;
}

extern "C" void kernel_launch(void* const* d_in, const int* in_sizes, int n_in,
                              void* d_out, int out_size, void* d_ws, size_t ws_size,
                              hipStream_t stream) {
    const float* X  = (const float*)d_in[0];
    const float* W1 = (const float*)d_in[1];
    const float* b1 = (const float*)d_in[2];
    const float* W2 = (const float*)d_in[3];
    const float* b2 = (const float*)d_in[4];
    const float* W3 = (const float*)d_in[5];
    const float* b3 = (const float*)d_in[6];
    const float* pa = (const float*)d_in[7];
    const int* ei   = (const int*)d_in[8];
    const int* src = ei;
    const int* dst = ei + EB;
    float* out = (float*)d_out;

    char* p = (char*)d_ws;
    int* bins   = (int*)carve(p, NBINS * sizeof(int));
    int* rs     = (int*)carve(p, (NBINS + 1) * sizeof(int));
    int* cursor = (int*)carve(p, NBINS * sizeof(int));
    int2* edges = (int2*)carve(p, EB * sizeof(int2));
    float* dinv = (float*)carve(p, NB * sizeof(float));

    size_t fixed = (size_t)(p - (char*)d_ws);
    size_t need_fused = fixed + 2 * ((size_t)2 * NB * 256 * sizeof(float) + 256);
    bool fused = ws_size >= need_fused;
    size_t rows = fused ? 2 * NB : NB;
    float* bufA = (float*)carve(p, rows * 256 * sizeof(float));
    float* bufB = (float*)carve(p, rows * 256 * sizeof(float));

    // --- tile-CSR build (once, reused by all aggregations) ---
    zero_kernel<<<(NBINS + 255) / 256, 256, 0, stream>>>(bins, NBINS);
    hist_kernel<<<(EB + 255) / 256, 256, 0, stream>>>(src, dst, bins);
    scan_kernel<<<1, 1024, 0, stream>>>(bins, rs, cursor);
    dinv_kernel<<<(NB + 255) / 256, 256, 0, stream>>>(rs, dinv);
    scatter_kernel<<<(EB + 255) / 256, 256, 0, stream>>>(src, dst, dinv, cursor, edges);

    int nbatch_loops = fused ? 1 : 2;
    for (int b = 0; b < nbatch_loops; ++b) {
        const float* Xb = X + (size_t)b * NB * DIN;
        float* outb = out + (size_t)b * NB * DOUTD;
        int M = (int)rows;
        int aggGrid = (M + 4 * RPW - 1) / (4 * RPW);  // fused: 1250 (all resident)

        // Layer 1: aggregate X (F=128), then GEMM(+b1,+prelu).
        agg2_kernel<128, false, false><<<aggGrid, 256, 0, stream>>>(
            Xb, bufA, rs, edges, dinv, nullptr, nullptr, M);
        gemm_kernel<true, true><<<dim3((M + 63) / 64, H1D / 64), 256, 0, stream>>>(
            bufA, M, DIN, W1, H1D, b1, pa, bufB);

        // Layer 2: GEMM then aggregate (+b2,+prelu).
        gemm_kernel<false, false><<<dim3((M + 63) / 64, H2D / 64), 256, 0, stream>>>(
            bufB, M, H1D, W2, H2D, nullptr, nullptr, bufA);
        agg2_kernel<256, true, true><<<aggGrid, 256, 0, stream>>>(
            bufA, bufB, rs, edges, dinv, b2, pa, M);

        // Layer 3: GEMM then aggregate (+b3, no prelu) -> output.
        gemm_kernel<false, false><<<dim3((M + 63) / 64, DOUTD / 64), 256, 0, stream>>>(
            bufB, M, H2D, W3, DOUTD, nullptr, nullptr, bufA);
        agg2_kernel<128, true, false><<<aggGrid, 256, 0, stream>>>(
            bufA, outb, rs, edges, dinv, b3, nullptr, M);
    }
}

// Round 4
// 394.923 us; speedup vs baseline: 1.7097x; 1.7097x over previous
//
#include <hip/hip_runtime.h>

#define NB 20000
#define EB 320000
#define DIN 128
#define H1D 256
#define H2D 256
#define DOUTD 128
#define SCAN_BLOCKS ((NB + 255) / 256)   // 79

// ---------------------------------------------------------------------------
// CSR build: histogram -> parallel 3-phase scan -> dinv -> counting-sort
// scatter into int2{src, w_bits} edge records sorted by dst.
// ---------------------------------------------------------------------------

__global__ void zero_kernel(int* __restrict__ p, int n) {
    int t = blockIdx.x * blockDim.x + threadIdx.x;
    if (t < n) p[t] = 0;
}

__global__ void hist_kernel(const int* __restrict__ dst, int* __restrict__ bins) {
    int t = blockIdx.x * blockDim.x + threadIdx.x;
    if (t < EB) atomicAdd(&bins[dst[t]], 1);
}

// Phase A: per-block (256-wide) scan; write local exclusive prefix + block sum.
__global__ __launch_bounds__(256) void scanA_kernel(const int* __restrict__ bins,
                                                    int* __restrict__ loc,
                                                    int* __restrict__ blksum) {
    __shared__ int s[256];
    int t = threadIdx.x;
    int i = blockIdx.x * 256 + t;
    int v = (i < NB) ? bins[i] : 0;
    s[t] = v;
    __syncthreads();
    for (int off = 1; off < 256; off <<= 1) {
        int u = (t >= off) ? s[t - off] : 0;
        __syncthreads();
        s[t] += u;
        __syncthreads();
    }
    if (i < NB) loc[i] = s[t] - v;  // exclusive within block
    if (t == 255) blksum[blockIdx.x] = s[255];
}

// Phase B: single small block scans the 79 block sums (in-place exclusive).
__global__ __launch_bounds__(128) void scanB_kernel(int* __restrict__ blksum) {
    __shared__ int s[128];
    int t = threadIdx.x;
    int v = (t < SCAN_BLOCKS) ? blksum[t] : 0;
    s[t] = v;
    __syncthreads();
    for (int off = 1; off < 128; off <<= 1) {
        int u = (t >= off) ? s[t - off] : 0;
        __syncthreads();
        s[t] += u;
        __syncthreads();
    }
    if (t < SCAN_BLOCKS) blksum[t] = s[t] - v;  // exclusive
}

// Phase C: rs = loc + blockoffset; cursor copy; dinv from bins.
__global__ __launch_bounds__(256) void scanC_kernel(const int* __restrict__ bins,
                                                    const int* __restrict__ loc,
                                                    const int* __restrict__ blksum,
                                                    int* __restrict__ rs,
                                                    int* __restrict__ cursor,
                                                    float* __restrict__ dinv) {
    int i = blockIdx.x * 256 + threadIdx.x;
    if (i < NB) {
        int r = loc[i] + blksum[blockIdx.x];
        rs[i] = r;
        cursor[i] = r;
        dinv[i] = rsqrtf((float)bins[i] + 1.0f);  // deg = in-degree + 1 (self loop)
    }
    if (i == 0) rs[NB] = EB;
}

__global__ void scatter_kernel(const int* __restrict__ src, const int* __restrict__ dst,
                               const float* __restrict__ dinv,
                               int* __restrict__ cursor, int2* __restrict__ edges) {
    int t = blockIdx.x * blockDim.x + threadIdx.x;
    if (t < EB) {
        int d = dst[t], s = src[t];
        int p = atomicAdd(&cursor[d], 1);
        edges[p] = make_int2(s, __float_as_int(dinv[s] * dinv[d]));
    }
}

// ---------------------------------------------------------------------------
// Batch-paired aggregation. Buffers use node-interleaved layout
// [node*2 + batch][F] (GEMMs are row-independent so they run unchanged).
// One WAVE per node handles BOTH batches: lanes 0-31 = batch0 features,
// lanes 32-63 = batch1. One float4-chunk set per lane per edge; edge record
// read once; 4-edge unroll -> >=4 loads in flight.
// SPLIT_IN:  gather source is batch-split [b][node][F] (the X input).
// SPLIT_OUT: store to batch-split [b][node][F] (the final output).
// ---------------------------------------------------------------------------

template <int NC>
__device__ inline void ldrow(float4 (&d)[NC], const float* __restrict__ p) {
#pragma unroll
    for (int c = 0; c < NC; ++c) d[c] = ((const float4*)p)[c];
}
template <int NC>
__device__ inline void fmarow(float4 (&a)[NC], const float4 (&t)[NC], float w) {
#pragma unroll
    for (int c = 0; c < NC; ++c) {
        a[c].x = fmaf(t[c].x, w, a[c].x);
        a[c].y = fmaf(t[c].y, w, a[c].y);
        a[c].z = fmaf(t[c].z, w, a[c].z);
        a[c].w = fmaf(t[c].w, w, a[c].w);
    }
}

template <int F, bool SPLIT_IN, bool SPLIT_OUT, bool BIAS, bool PRELU>
__global__ __launch_bounds__(256) void agg_kernel(
    const float* __restrict__ h, float* __restrict__ out,
    const int* __restrict__ rs, const int2* __restrict__ edges,
    const float* __restrict__ dinv, const float* __restrict__ bias,
    const float* __restrict__ pa) {
    constexpr int V2 = 2 * F / 64;   // floats per lane (4 or 8)
    constexpr int NC = V2 / 4;       // float4 chunks per lane (1 or 2)
    constexpr int GSTRIDE = SPLIT_IN ? F : 2 * F;
    int node = blockIdx.x * 4 + (threadIdx.x >> 6);  // NB % 4 == 0
    int lane = threadIdx.x & 63;
    int b = lane >> 5;
    int fl = (lane & 31) * V2;       // feature offset within F

    const float* gbase = SPLIT_IN ? (h + (size_t)b * NB * F + fl)
                                  : (h + (size_t)lane * V2);

    float4 acc0[NC], acc1[NC], acc2[NC], acc3[NC];
    {   // self loop
        float dv = dinv[node];
        float sw = dv * dv;
        float4 tv[NC];
        ldrow<NC>(tv, gbase + (size_t)node * GSTRIDE);
#pragma unroll
        for (int c = 0; c < NC; ++c) {
            acc0[c] = make_float4(tv[c].x * sw, tv[c].y * sw, tv[c].z * sw, tv[c].w * sw);
            acc1[c] = make_float4(0.f, 0.f, 0.f, 0.f);
            acc2[c] = make_float4(0.f, 0.f, 0.f, 0.f);
            acc3[c] = make_float4(0.f, 0.f, 0.f, 0.f);
        }
    }

    int e0 = __builtin_amdgcn_readfirstlane(rs[node]);
    int e1 = __builtin_amdgcn_readfirstlane(rs[node + 1]);
    int e = e0;
    for (; e + 4 <= e1; e += 4) {
        int2 d0 = edges[e], d1 = edges[e + 1], d2 = edges[e + 2], d3 = edges[e + 3];
        float4 t0[NC], t1[NC], t2[NC], t3[NC];
        ldrow<NC>(t0, gbase + (size_t)d0.x * GSTRIDE);
        ldrow<NC>(t1, gbase + (size_t)d1.x * GSTRIDE);
        ldrow<NC>(t2, gbase + (size_t)d2.x * GSTRIDE);
        ldrow<NC>(t3, gbase + (size_t)d3.x * GSTRIDE);
        fmarow<NC>(acc0, t0, __int_as_float(d0.y));
        fmarow<NC>(acc1, t1, __int_as_float(d1.y));
        fmarow<NC>(acc2, t2, __int_as_float(d2.y));
        fmarow<NC>(acc3, t3, __int_as_float(d3.y));
    }
    for (; e < e1; ++e) {
        int2 d0 = edges[e];
        float4 t0[NC];
        ldrow<NC>(t0, gbase + (size_t)d0.x * GSTRIDE);
        fmarow<NC>(acc0, t0, __int_as_float(d0.y));
    }

#pragma unroll
    for (int c = 0; c < NC; ++c) {
        acc0[c].x += (acc1[c].x + acc2[c].x) + acc3[c].x;
        acc0[c].y += (acc1[c].y + acc2[c].y) + acc3[c].y;
        acc0[c].z += (acc1[c].z + acc2[c].z) + acc3[c].z;
        acc0[c].w += (acc1[c].w + acc2[c].w) + acc3[c].w;
    }
    if (BIAS) {
        float4 bv[NC];
        ldrow<NC>(bv, bias + fl);
#pragma unroll
        for (int c = 0; c < NC; ++c) {
            acc0[c].x += bv[c].x; acc0[c].y += bv[c].y;
            acc0[c].z += bv[c].z; acc0[c].w += bv[c].w;
        }
    }
    if (PRELU) {
        float a = *pa;
#pragma unroll
        for (int c = 0; c < NC; ++c) {
            acc0[c].x = acc0[c].x >= 0.f ? acc0[c].x : a * acc0[c].x;
            acc0[c].y = acc0[c].y >= 0.f ? acc0[c].y : a * acc0[c].y;
            acc0[c].z = acc0[c].z >= 0.f ? acc0[c].z : a * acc0[c].z;
            acc0[c].w = acc0[c].w >= 0.f ? acc0[c].w : a * acc0[c].w;
        }
    }
    float* obase = SPLIT_OUT ? (out + (size_t)b * NB * F + (size_t)node * F + fl)
                             : (out + (size_t)node * 2 * F + lane * V2);
#pragma unroll
    for (int c = 0; c < NC; ++c) ((float4*)obase)[c] = acc0[c];
}

// ---------------------------------------------------------------------------
// FP32 GEMM: C[M,Nc] = A[M,K] @ W[K,Nc] (+bias) (+prelu).
// 128x64 tile, BK=16, 256 threads, 8x4 microtile: 32 FMA per 3 ds_read_b128.
// ---------------------------------------------------------------------------
template <bool BIAS, bool PRELU>
__global__ __launch_bounds__(256) void gemm_kernel(const float* __restrict__ A, int M, int K,
                                                   const float* __restrict__ W, int Nc,
                                                   const float* __restrict__ bias,
                                                   const float* __restrict__ pa,
                                                   float* __restrict__ C) {
    __shared__ alignas(16) float As[16][132];  // [k][m], pad 132 (528 B rows, 16B-aligned)
    __shared__ alignas(16) float Bs[16][68];   // [k][n]
    int t = threadIdx.x;
    int bm = blockIdx.x * 128;
    int bn = blockIdx.y * 64;
    int tx = t & 15, ty = t >> 4;
    int m0 = ty * 8, n0 = tx * 4;
    int ar = t >> 2, ac4 = (t & 3) * 4;   // A: rows ar, ar+64; k-cols ac4..ac4+3
    int br = t >> 4, bc4 = (t & 15) * 4;  // B: row br, cols bc4..bc4+3

    float acc[8][4] = {};

    for (int k0 = 0; k0 < K; k0 += 16) {
        float4 a0 = make_float4(0.f, 0.f, 0.f, 0.f), a1 = a0;
        int r0 = bm + ar, r1 = bm + ar + 64;
        if (r0 < M) a0 = *(const float4*)&A[(size_t)r0 * K + k0 + ac4];
        if (r1 < M) a1 = *(const float4*)&A[(size_t)r1 * K + k0 + ac4];
        As[ac4 + 0][ar] = a0.x; As[ac4 + 1][ar] = a0.y;
        As[ac4 + 2][ar] = a0.z; As[ac4 + 3][ar] = a0.w;
        As[ac4 + 0][ar + 64] = a1.x; As[ac4 + 1][ar + 64] = a1.y;
        As[ac4 + 2][ar + 64] = a1.z; As[ac4 + 3][ar + 64] = a1.w;
        float4 bv = *(const float4*)&W[(size_t)(k0 + br) * Nc + bn + bc4];
        *(float4*)&Bs[br][bc4] = bv;
        __syncthreads();
#pragma unroll
        for (int k = 0; k < 16; ++k) {
            float4 av0 = *(const float4*)&As[k][m0];
            float4 av1 = *(const float4*)&As[k][m0 + 4];
            float4 bv4 = *(const float4*)&Bs[k][n0];
            float a_[8] = {av0.x, av0.y, av0.z, av0.w, av1.x, av1.y, av1.z, av1.w};
            float b_[4] = {bv4.x, bv4.y, bv4.z, bv4.w};
#pragma unroll
            for (int i = 0; i < 8; ++i)
#pragma unroll
                for (int j = 0; j < 4; ++j)
                    acc[i][j] = fmaf(a_[i], b_[j], acc[i][j]);
        }
        __syncthreads();
    }

    float pav = 0.0f;
    if (PRELU) pav = *pa;
#pragma unroll
    for (int i = 0; i < 8; ++i) {
        int row = bm + m0 + i;
        if (row < M) {
            float v[4];
#pragma unroll
            for (int j = 0; j < 4; ++j) {
                float x = acc[i][j];
                if (BIAS) x += bias[bn + n0 + j];
                if (PRELU) x = (x >= 0.0f) ? x : pav * x;
                v[j] = x;
            }
            *(float4*)&C[(size_t)row * Nc + bn + n0] = make_float4(v[0], v[1], v[2], v[3]);
        }
    }
}

// ---------------------------------------------------------------------------

static inline char* carve(char*& p, size_t bytes) {
    char* r = p;
    p += (bytes + 255) & ~(size_t)255;
    return r;
}

extern "C" void kernel_launch(void* const* d_in, const int* in_sizes, int n_in,
                              void* d_out, int out_size, void* d_ws, size_t ws_size,
                              hipStream_t stream) {
    const float* X  = (const float*)d_in[0];
    const float* W1 = (const float*)d_in[1];
    const float* b1 = (const float*)d_in[2];
    const float* W2 = (const float*)d_in[3];
    const float* b2 = (const float*)d_in[4];
    const float* W3 = (const float*)d_in[5];
    const float* b3 = (const float*)d_in[6];
    const float* pa = (const float*)d_in[7];
    const int* ei   = (const int*)d_in[8];
    const int* src = ei;
    const int* dst = ei + EB;
    float* out = (float*)d_out;

    char* p = (char*)d_ws;
    int* bins    = (int*)carve(p, NB * sizeof(int));
    int* loc     = (int*)carve(p, NB * sizeof(int));
    int* blksum  = (int*)carve(p, 128 * sizeof(int));
    int* rs      = (int*)carve(p, (NB + 1) * sizeof(int));
    int* cursor  = (int*)carve(p, NB * sizeof(int));
    int2* edges  = (int2*)carve(p, EB * sizeof(int2));
    float* dinv  = (float*)carve(p, NB * sizeof(float));
    float* bufA  = (float*)carve(p, (size_t)2 * NB * 256 * sizeof(float));
    float* bufB  = (float*)carve(p, (size_t)2 * NB * 256 * sizeof(float));

    const int M = 2 * NB;  // fused batch rows, node-interleaved [node*2+b][F]

    // --- CSR build ---
    zero_kernel<<<SCAN_BLOCKS, 256, 0, stream>>>(bins, NB);
    hist_kernel<<<(EB + 255) / 256, 256, 0, stream>>>(dst, bins);
    scanA_kernel<<<SCAN_BLOCKS, 256, 0, stream>>>(bins, loc, blksum);
    scanB_kernel<<<1, 128, 0, stream>>>(blksum);
    scanC_kernel<<<SCAN_BLOCKS, 256, 0, stream>>>(bins, loc, blksum, rs, cursor, dinv);
    scatter_kernel<<<(EB + 255) / 256, 256, 0, stream>>>(src, dst, dinv, cursor, edges);

    const int aggGrid = NB / 4;  // one wave per node, 4 waves/block

    // Layer 1: aggregate X (split layout) -> bufA interleaved; GEMM(+b1,+prelu).
    agg_kernel<128, true, false, false, false><<<aggGrid, 256, 0, stream>>>(
        X, bufA, rs, edges, dinv, nullptr, nullptr);
    gemm_kernel<true, true><<<dim3((M + 127) / 128, H1D / 64), 256, 0, stream>>>(
        bufA, M, DIN, W1, H1D, b1, pa, bufB);

    // Layer 2: GEMM then aggregate (+b2,+prelu), interleaved -> interleaved.
    gemm_kernel<false, false><<<dim3((M + 127) / 128, H2D / 64), 256, 0, stream>>>(
        bufB, M, H1D, W2, H2D, nullptr, nullptr, bufA);
    agg_kernel<256, false, false, true, true><<<aggGrid, 256, 0, stream>>>(
        bufA, bufB, rs, edges, dinv, b2, pa);

    // Layer 3: GEMM then aggregate (+b3, no prelu) -> batch-split output.
    gemm_kernel<false, false><<<dim3((M + 127) / 128, DOUTD / 64), 256, 0, stream>>>(
        bufB, M, H2D, W3, DOUTD, nullptr, nullptr, bufA);
    agg_kernel<128, false, true, true, false><<<aggGrid, 256, 0, stream>>>(
        bufA, out, rs, edges, dinv, b3, nullptr);
}